// Round 21
// baseline (69.325 us; speedup 1.0000x reference)
//
#include <hip/hip_runtime.h>
#include <hip/hip_fp16.h>
#include <math.h>

// MPS-RNN 2D forward: L=8, M=8, DCUT=6, HL=2, N=64, B=32768
// Round-21 = round-20 + 2 samples per thread (ILP2):
//   block = 128 samples (sA = s, sB = s+64), grid = 256 = 1 block/CU.
//   T/M rows, VE, W/C loads are sample-independent -> shared between the two
//   chains: LDS instr/sample 20 -> ~10.5, register loads amortized, 2-way
//   ILP replaces the lost 2nd wave/SIMD. At 1 wave/SIMD VGPR<=256 is free.
// Repack kernel + pure-copy staging + row-boundary bypass retained from r20.
// Fallback to r16-style kernel if ws too small.

#define NQ  64
#define BT  256
#define CHUNK_U 5184   // uints per chunk image: 4608 T/M | 512 VE(f32) | 64 Wl

typedef _Float16 h2v __attribute__((ext_vector_type(2)));
typedef __fp16  p2v __attribute__((ext_vector_type(2)));
union H2U { unsigned u; h2v h; __half2 hh; };

static __device__ __forceinline__ h2v pack2(float a, float b) {
    p2v p = __builtin_amdgcn_cvt_pkrtz(a, b);
    h2v r; __builtin_memcpy(&r, &p, sizeof(r));
    return r;
}
static __device__ __forceinline__ h2v u2h(unsigned u) {
    h2v r; __builtin_memcpy(&r, &u, sizeof(r));
    return r;
}
static __device__ __forceinline__ unsigned h2u(h2v h) {
    unsigned r; __builtin_memcpy(&r, &h, sizeof(r));
    return r;
}

#define DPPF(x, ctrl) __int_as_float(__builtin_amdgcn_update_dpp(            \
    __float_as_int(x), __float_as_int(x), (ctrl), 0xF, 0xF, false))
#define QP_XOR1 0xB1
#define QP_XOR2 0x4E
#define QP_BC0  0x00
#define QP_BC1  0x55

#if defined(__has_builtin)
#  if __has_builtin(__builtin_amdgcn_rcpf)
#    define FAST_RCP(x) __builtin_amdgcn_rcpf(x)
#  else
#    define FAST_RCP(x) (1.0f / (x))
#  endif
#  if __has_builtin(__builtin_amdgcn_rsqf)
#    define FAST_RSQ(x) __builtin_amdgcn_rsqf(x)
#  else
#    define FAST_RSQ(x) rsqrtf(x)
#  endif
#  if __has_builtin(__builtin_amdgcn_fdot2)
#    define HAS_FDOT2 1
#  endif
#else
#  define FAST_RCP(x) (1.0f / (x))
#  define FAST_RSQ(x) rsqrtf(x)
#endif

static __device__ __forceinline__ float fdot2u(unsigned a, h2v b, float c) {
#ifdef HAS_FDOT2
    H2U u; u.u = a;
    return __builtin_amdgcn_fdot2(u.h, b, c, false);
#else
    H2U u; u.u = a;
    return fmaf((float)u.h.x, (float)b.x, fmaf((float)u.h.y, (float)b.y, c));
#endif
}

// ---------- one-time param repack (grid 4 = one block per 16-site chunk) ----
__global__ void repack_k(
    const float* __restrict__ Mh, const float* __restrict__ Mv,
    const float* __restrict__ Vp, const float* __restrict__ Tp,
    const float* __restrict__ Wp, const float* __restrict__ Cp,
    const float* __restrict__ Ep, unsigned* __restrict__ ws)
{
    const int ch = blockIdx.x;
    const int t  = threadIdx.x;
    unsigned* Tm = ws + ch * CHUNK_U;
    float*    VE = reinterpret_cast<float*>(Tm + 4608);
    uint4*    Wl = reinterpret_cast<uint4*>(Tm + 4608 + 512);

    const float2* gT = reinterpret_cast<const float2*>(Tp + ch * 6912);
    for (int p = t; p < 3456; p += BT) {
        int site = p / 216, rr = p - site * 216;
        int row = rr / 18,  w  = rr - row * 18;
        float2 v = gT[p];
        H2U hu; hu.hh = __floats2half2_rn(v.x, v.y);
        Tm[(site * 12 + row) * 24 + w] = hu.u;
    }
    const float2* gH = reinterpret_cast<const float2*>(Mh + ch * 1152);
    const float2* gV = reinterpret_cast<const float2*>(Mv + ch * 1152);
    for (int p = t; p < 576; p += BT) {
        int site = p / 36, rr = p - site * 36;
        int row = rr / 3,  w  = rr - row * 3;
        int o_r = row - ((row >= 6) ? 6 : 0);     // row % 6
        float2 vh = gH[p], vv2 = gV[p];
        if ((o_r >> 1) == w) {                    // residual diag fold (+1)
            if (o_r & 1) { vh.y += 1.f; vv2.y += 1.f; }
            else         { vh.x += 1.f; vv2.x += 1.f; }
        }
        H2U a; a.hh = __floats2half2_rn(vh.x, vh.y);
        H2U c; c.hh = __floats2half2_rn(vv2.x, vv2.y);
        Tm[(site * 12 + row) * 24 + 18 + w] = a.u;
        Tm[(site * 12 + row) * 24 + 21 + w] = c.u;
    }
    if (t < 192) {
        int site = t / 12, q = t - site * 12;
        int sb = q / 3,    c = q - sb * 3;
        VE[(site * 4 + sb) * 8 + c] = Vp[ch * 192 + t];
        float e = Ep[ch * 96 + site * 6 + (sb & 1) * 3 + c];
        VE[(site * 4 + sb) * 8 + 3 + c] = e * e;
    } else if (t < 208) {
        int site = t - 192;
        const float2* gw = reinterpret_cast<const float2*>(Wp) + ch * 48 + site * 3;
        float2 w01 = gw[0], w23 = gw[1], w45 = gw[2];
        H2U u0, u1, u2;
        u0.hh = __floats2half2_rn(w01.x, w01.y);
        u1.hh = __floats2half2_rn(w23.x, w23.y);
        u2.hh = __floats2half2_rn(w45.x, w45.y);
        Wl[site] = make_uint4(u0.u, u1.u, u2.u,
                              __float_as_uint(Cp[ch * 16 + site]));
    }
}

// ---------- per-sample bit pack helper (device) ------------------------------
static __device__ __forceinline__ unsigned long long pack_bits(
    const int* X, int b, int sub)
{
    const int4* xr = reinterpret_cast<const int4*>(X + (size_t)b * NQ + sub * 16);
    unsigned long long part = 0ull;
    #pragma unroll
    for (int q = 0; q < 4; ++q) {
        int4 v = xr[q];
        part |= (unsigned long long)(v.x & 1) << (4 * q + 0);
        part |= (unsigned long long)(v.y & 1) << (4 * q + 1);
        part |= (unsigned long long)(v.z & 1) << (4 * q + 2);
        part |= (unsigned long long)(v.w & 1) << (4 * q + 3);
    }
    unsigned long long bits = part << (16 * sub);
    bits |= __shfl_xor(bits, 1, 64);
    bits |= __shfl_xor(bits, 2, 64);
    return bits;
}

// ---------- main kernel: 2 samples/thread (ILP2) -----------------------------
__global__ __launch_bounds__(BT, 1) void mps_rnn21(
    const unsigned* __restrict__ ws,
    const int* __restrict__ X,
    float* __restrict__ out, int Bn, int writeImag)
{
    __shared__ uint4    ldsb[CHUNK_U / 4];   // 20736 B chunk image
    __shared__ unsigned vsm[8 * 128 * 4];    // 16384 B vertical state [j][s128][4]

    unsigned*     Tl = reinterpret_cast<unsigned*>(ldsb);
    const float*  VE = reinterpret_cast<const float*>(Tl + 4608);
    const uint4*  Wl = reinterpret_cast<const uint4*>(Tl + 4608 + 512);

    const int t   = threadIdx.x;
    const int sub = t & 3;
    const int s   = t >> 2;
    int bA = blockIdx.x * 128 + s;
    int bB = bA + 64;
    const bool vA = (bA < Bn), vB = (bB < Bn);
    if (!vA) bA = Bn - 1;
    if (!vB) bB = Bn - 1;

    const unsigned long long bitsA = pack_bits(X, bA, sub);
    const unsigned long long bitsB = pack_bits(X, bB, sub);

    for (int u = t; u < 8 * 128 * 4; u += BT) vsm[u] = 0u;

    const int mya = sub >> 1;

    float hhA[6], hhB[6];
    h2v hap0, hap1, hap2, hbp0, hbp1, hbp2;
    float amp2A = 1.f, phiA = 0.f, amp2B = 1.f, phiB = 0.f;

    for (int ch = 0; ch < 4; ++ch) {
        __syncthreads();             // previous chunk fully consumed
        {
            const uint4* g4 = reinterpret_cast<const uint4*>(ws + ch * CHUNK_U);
            #pragma unroll
            for (int i = 0; i < 6; ++i) {
                int idx = t + i * BT;
                if (idx < CHUNK_U / 4) ldsb[idx] = g4[idx];
            }
        }
        __syncthreads();             // chunk visible

        #pragma unroll
        for (int ih = 0; ih < 2; ++ih) {
            const unsigned cbrA = (unsigned)(bitsA >> (ch * 16 + ih * 8)) & 0xFFu;
            const unsigned cbrB = (unsigned)(bitsB >> (ch * 16 + ih * 8)) & 0xFFu;

            #pragma unroll 2
            for (int qq = 0; qq < 8; ++qq) {
                const int j    = ih ? 7 - qq : qq;      // snake column
                const int slot = ih * 8 + j;

                const unsigned* Tb = Tl + (slot * 12 + sub * 3) * 24;
                const float*   VEb = VE + (slot * 4 + sub) * 8;

                h2v va0, va1, va2, vb0, vb1, vb2;       // hv packed, A and B
                if (qq == 0) {
                    if (ch == 0 && ih == 0) {
                        H2U z; z.u = 0u;
                        va0 = z.h; va1 = z.h; va2 = z.h;
                        vb0 = z.h; vb1 = z.h; vb2 = z.h;
                    } else {                            // row-boundary bypass
                        va0 = hap0; va1 = hap1; va2 = hap2;
                        vb0 = hbp0; vb1 = hbp1; vb2 = hbp2;
                    }
                    #pragma unroll
                    for (int o = 0; o < 6; ++o) { hhA[o] = 1.f; hhB[o] = 1.f; }
                    H2U one; one.u = 0x3C003C00u;
                    hap0 = one.h; hap1 = one.h; hap2 = one.h;
                    hbp0 = one.h; hbp1 = one.h; hbp2 = one.h;
                } else {
                    uint4 ha = *reinterpret_cast<const uint4*>(vsm + j * 512 + s * 4);
                    uint4 hb = *reinterpret_cast<const uint4*>(vsm + j * 512 + (s + 64) * 4);
                    va0 = u2h(ha.x); va1 = u2h(ha.y); va2 = u2h(ha.z);
                    vb0 = u2h(hb.x); vb1 = u2h(hb.y); vb2 = u2h(hb.z);
                }

                float4 ve0 = *reinterpret_cast<const float4*>(VEb);     // v0 v1 v2 e0^2
                float2 ve1 = *reinterpret_cast<const float2*>(VEb + 4); // e1^2 e2^2
                const float vv_[3] = { ve0.x, ve0.y, ve0.z };
                const float e2_[3] = { ve0.w, ve1.x, ve1.y };

                float accA[3], accB[3];
                #pragma unroll
                for (int lr = 0; lr < 3; ++lr) {
                    const unsigned* Tr = Tb + lr * 24;
                    uint4 tA4 = *reinterpret_cast<const uint4*>(Tr);
                    uint4 tB4 = *reinterpret_cast<const uint4*>(Tr + 4);
                    uint4 tC4 = *reinterpret_cast<const uint4*>(Tr + 8);
                    uint4 tD4 = *reinterpret_cast<const uint4*>(Tr + 12);
                    uint4 tE4 = *reinterpret_cast<const uint4*>(Tr + 16);
                    uint4 tF4 = *reinterpret_cast<const uint4*>(Tr + 20);
                    const unsigned tw[18] = {tA4.x,tA4.y,tA4.z,tA4.w,
                                             tB4.x,tB4.y,tB4.z,tB4.w,
                                             tC4.x,tC4.y,tC4.z,tC4.w,
                                             tD4.x,tD4.y,tD4.z,tD4.w,
                                             tE4.x,tE4.y};
                    // ---- sample A
                    float scA[6];
                    #pragma unroll
                    for (int c = 0; c < 6; ++c)
                        scA[c] = fdot2u(tw[c*3+0], va0,
                                 fdot2u(tw[c*3+1], va1,
                                 fdot2u(tw[c*3+2], va2, 0.f)));
                    float taA = fmaf(scA[0], hhA[0], fmaf(scA[2], hhA[2], scA[4]*hhA[4]));
                    float tbA = fmaf(scA[1], hhA[1], fmaf(scA[3], hhA[3], scA[5]*hhA[5]));
                    float mdA = fdot2u(tE4.z, hap0, fdot2u(tE4.w, hap1,
                                fdot2u(tF4.x, hap2, vv_[lr])));
                    float ndA = fdot2u(tF4.y, va0, fdot2u(tF4.z, va1,
                                fdot2u(tF4.w, va2, 0.f)));
                    accA[lr] = (taA + tbA) + (mdA + ndA);
                    // ---- sample B (same tw/tE/tF registers)
                    float scB[6];
                    #pragma unroll
                    for (int c = 0; c < 6; ++c)
                        scB[c] = fdot2u(tw[c*3+0], vb0,
                                 fdot2u(tw[c*3+1], vb1,
                                 fdot2u(tw[c*3+2], vb2, 0.f)));
                    float taB = fmaf(scB[0], hhB[0], fmaf(scB[2], hhB[2], scB[4]*hhB[4]));
                    float tbB = fmaf(scB[1], hhB[1], fmaf(scB[3], hhB[3], scB[5]*hhB[5]));
                    float mdB = fdot2u(tE4.z, hbp0, fdot2u(tE4.w, hbp1,
                                fdot2u(tF4.x, hbp2, vv_[lr])));
                    float ndB = fdot2u(tF4.y, vb0, fdot2u(tF4.z, vb1,
                                fdot2u(tF4.w, vb2, 0.f)));
                    accB[lr] = (taB + tbB) + (mdB + ndB);
                }

                const uint4 wv = Wl[slot];
                const int selA = (cbrA >> qq) & 1;
                const int selB = (cbrB >> qq) & 1;

                // ---- sample A tail
                {
                    float q0 = accA[0]*accA[0], q1 = accA[1]*accA[1], q2 = accA[2]*accA[2];
                    float ssl = (q0 + q1) + q2;
                    float pq  = fmaf(e2_[0], q0, fmaf(e2_[1], q1, e2_[2] * q2));
                    float s1  = ssl + DPPF(ssl, QP_XOR1);
                    float ssq = s1 + DPPF(s1, QP_XOR2);
                    float p1  = pq + DPPF(pq, QP_XOR1);
                    float px  = DPPF(p1, QP_XOR2);
                    const float inv = FAST_RSQ(ssq + 1e-12f);
                    const float qsel = (mya == selA) ? p1 : px;
                    amp2A *= qsel * FAST_RCP(p1 + px);
                    float a0 = accA[0]*inv, a1 = accA[1]*inv, a2 = accA[2]*inv;
                    float w0 = DPPF(a0, QP_XOR2), w1 = DPPF(a1, QP_XOR2), w2 = DPPF(a2, QP_XOR2);
                    a0 = selA ? w0 : a0; a1 = selA ? w1 : a1; a2 = selA ? w2 : a2;
                    hhA[0] = DPPF(a0, QP_BC0); hhA[3] = DPPF(a0, QP_BC1);
                    hhA[1] = DPPF(a1, QP_BC0); hhA[4] = DPPF(a1, QP_BC1);
                    hhA[2] = DPPF(a2, QP_BC0); hhA[5] = DPPF(a2, QP_BC1);
                    hap0 = pack2(hhA[0], hhA[1]);
                    hap1 = pack2(hhA[2], hhA[3]);
                    hap2 = pack2(hhA[4], hhA[5]);
                    phiA = fdot2u(wv.x, hap0, fdot2u(wv.y, hap1,
                           fdot2u(wv.z, hap2, __uint_as_float(wv.w) + phiA)));
                }
                // ---- sample B tail
                {
                    float q0 = accB[0]*accB[0], q1 = accB[1]*accB[1], q2 = accB[2]*accB[2];
                    float ssl = (q0 + q1) + q2;
                    float pq  = fmaf(e2_[0], q0, fmaf(e2_[1], q1, e2_[2] * q2));
                    float s1  = ssl + DPPF(ssl, QP_XOR1);
                    float ssq = s1 + DPPF(s1, QP_XOR2);
                    float p1  = pq + DPPF(pq, QP_XOR1);
                    float px  = DPPF(p1, QP_XOR2);
                    const float inv = FAST_RSQ(ssq + 1e-12f);
                    const float qsel = (mya == selB) ? p1 : px;
                    amp2B *= qsel * FAST_RCP(p1 + px);
                    float a0 = accB[0]*inv, a1 = accB[1]*inv, a2 = accB[2]*inv;
                    float w0 = DPPF(a0, QP_XOR2), w1 = DPPF(a1, QP_XOR2), w2 = DPPF(a2, QP_XOR2);
                    a0 = selB ? w0 : a0; a1 = selB ? w1 : a1; a2 = selB ? w2 : a2;
                    hhB[0] = DPPF(a0, QP_BC0); hhB[3] = DPPF(a0, QP_BC1);
                    hhB[1] = DPPF(a1, QP_BC0); hhB[4] = DPPF(a1, QP_BC1);
                    hhB[2] = DPPF(a2, QP_BC0); hhB[5] = DPPF(a2, QP_BC1);
                    hbp0 = pack2(hhB[0], hhB[1]);
                    hbp1 = pack2(hhB[2], hhB[3]);
                    hbp2 = pack2(hhB[4], hhB[5]);
                    phiB = fdot2u(wv.x, hbp0, fdot2u(wv.y, hbp1,
                           fdot2u(wv.z, hbp2, __uint_as_float(wv.w) + phiB)));
                }

                if (sub == 0 && qq != 7) {
                    *reinterpret_cast<uint4*>(vsm + j * 512 + s * 4) =
                        make_uint4(h2u(hap0), h2u(hap1), h2u(hap2), 0u);
                    *reinterpret_cast<uint4*>(vsm + j * 512 + (s + 64) * 4) =
                        make_uint4(h2u(hbp0), h2u(hbp1), h2u(hbp2), 0u);
                }
            }
        }
    }

    if (sub == 0) {
        if (vA) {
            const float amp = sqrtf(amp2A);
            if (writeImag) {
                out[2 * bA + 0] = amp * cosf(phiA);
                out[2 * bA + 1] = amp * sinf(phiA);
            } else {
                out[bA] = amp * cosf(phiA);
            }
        }
        if (vB) {
            const float amp = sqrtf(amp2B);
            if (writeImag) {
                out[2 * bB + 0] = amp * cosf(phiB);
                out[2 * bB + 1] = amp * sinf(phiB);
            } else {
                out[bB] = amp * cosf(phiB);
            }
        }
    }
}

// ---------- fallback: r16-style kernel (in-kernel staging, 1 sample/thread) --
__global__ __launch_bounds__(BT, 1) void mps_rnn16fb(
    const float* __restrict__ Mh, const float* __restrict__ Mv,
    const float* __restrict__ Vp, const float* __restrict__ Tp,
    const float* __restrict__ Wp, const float* __restrict__ Cp,
    const float* __restrict__ Ep, const int* __restrict__ X,
    float* __restrict__ out, int Bn, int writeImag)
{
    __shared__ unsigned Tl[16 * 12 * 24];
    __shared__ float    VE [16 * 4 * 8];
    __shared__ uint4    Wl [16];
    __shared__ unsigned vsm[8 * 64 * 4];

    const int t   = threadIdx.x;
    const int sub = t & 3;
    const int s   = t >> 2;
    int b = blockIdx.x * 64 + s;
    const bool valid = (b < Bn);
    if (!valid) b = Bn - 1;

    unsigned long long bits = pack_bits(X, b, sub);
    for (int u = t; u < 8 * 64 * 4; u += BT) vsm[u] = 0u;
    const int mya = sub >> 1;
    float hh[6];
    h2v hhp0, hhp1, hhp2;
    float amp2 = 1.f, phi = 0.f;

    for (int ch = 0; ch < 4; ++ch) {
        __syncthreads();
        {
            const float2* gT = reinterpret_cast<const float2*>(Tp + ch * 6912);
            for (int p = t; p < 3456; p += BT) {
                int site = p / 216, rr = p - site * 216;
                int row = rr / 18,  w  = rr - row * 18;
                float2 v = gT[p];
                H2U hu; hu.hh = __floats2half2_rn(v.x, v.y);
                Tl[(site * 12 + row) * 24 + w] = hu.u;
            }
            const float2* gH = reinterpret_cast<const float2*>(Mh + ch * 1152);
            const float2* gV = reinterpret_cast<const float2*>(Mv + ch * 1152);
            for (int p = t; p < 576; p += BT) {
                int site = p / 36, rr = p - site * 36;
                int row = rr / 3,  w  = rr - row * 3;
                int o_r = row - ((row >= 6) ? 6 : 0);
                float2 vh = gH[p], vv2 = gV[p];
                if ((o_r >> 1) == w) {
                    if (o_r & 1) { vh.y += 1.f; vv2.y += 1.f; }
                    else         { vh.x += 1.f; vv2.x += 1.f; }
                }
                H2U a; a.hh = __floats2half2_rn(vh.x, vh.y);
                H2U c; c.hh = __floats2half2_rn(vv2.x, vv2.y);
                Tl[(site * 12 + row) * 24 + 18 + w] = a.u;
                Tl[(site * 12 + row) * 24 + 21 + w] = c.u;
            }
            if (t < 192) {
                int site = t / 12, q = t - site * 12;
                int sb = q / 3,    c = q - sb * 3;
                VE[(site * 4 + sb) * 8 + c] = Vp[ch * 192 + t];
                float e = Ep[ch * 96 + site * 6 + (sb & 1) * 3 + c];
                VE[(site * 4 + sb) * 8 + 3 + c] = e * e;
            } else if (t < 208) {
                int site = t - 192;
                const float2* gw = reinterpret_cast<const float2*>(Wp) + ch * 48 + site * 3;
                float2 w01 = gw[0], w23 = gw[1], w45 = gw[2];
                H2U u0, u1, u2;
                u0.hh = __floats2half2_rn(w01.x, w01.y);
                u1.hh = __floats2half2_rn(w23.x, w23.y);
                u2.hh = __floats2half2_rn(w45.x, w45.y);
                Wl[site] = make_uint4(u0.u, u1.u, u2.u,
                                      __float_as_uint(Cp[ch * 16 + site]));
            }
        }
        __syncthreads();

        #pragma unroll
        for (int ih = 0; ih < 2; ++ih) {
            const unsigned cbr = (unsigned)(bits >> (ch * 16 + ih * 8)) & 0xFFu;
            #pragma unroll 2
            for (int qq = 0; qq < 8; ++qq) {
                const int j    = ih ? 7 - qq : qq;
                const int slot = ih * 8 + j;
                const unsigned* Tb = Tl + (slot * 12 + sub * 3) * 24;
                const float*   VEb = VE + (slot * 4 + sub) * 8;
                if (qq == 0) {
                    #pragma unroll
                    for (int o = 0; o < 6; ++o) hh[o] = 1.f;
                    H2U one; one.u = 0x3C003C00u;
                    hhp0 = one.h; hhp1 = one.h; hhp2 = one.h;
                }
                uint4 hvu = *reinterpret_cast<const uint4*>(vsm + j * 256 + s * 4);
                const h2v hvh0 = u2h(hvu.x);
                const h2v hvh1 = u2h(hvu.y);
                const h2v hvh2 = u2h(hvu.z);
                float4 ve0 = *reinterpret_cast<const float4*>(VEb);
                float2 ve1 = *reinterpret_cast<const float2*>(VEb + 4);
                const float vv_[3] = { ve0.x, ve0.y, ve0.z };
                const float e2_[3] = { ve0.w, ve1.x, ve1.y };
                float acc[3];
                #pragma unroll
                for (int lr = 0; lr < 3; ++lr) {
                    const unsigned* Tr = Tb + lr * 24;
                    uint4 tA = *reinterpret_cast<const uint4*>(Tr);
                    uint4 tB = *reinterpret_cast<const uint4*>(Tr + 4);
                    uint4 tC = *reinterpret_cast<const uint4*>(Tr + 8);
                    uint4 tD = *reinterpret_cast<const uint4*>(Tr + 12);
                    uint4 tE = *reinterpret_cast<const uint4*>(Tr + 16);
                    uint4 tF = *reinterpret_cast<const uint4*>(Tr + 20);
                    const unsigned tw[18] = {tA.x,tA.y,tA.z,tA.w, tB.x,tB.y,tB.z,tB.w,
                                             tC.x,tC.y,tC.z,tC.w, tD.x,tD.y,tD.z,tD.w,
                                             tE.x,tE.y};
                    float sc[6];
                    #pragma unroll
                    for (int c = 0; c < 6; ++c)
                        sc[c] = fdot2u(tw[c*3+0], hvh0,
                                fdot2u(tw[c*3+1], hvh1,
                                fdot2u(tw[c*3+2], hvh2, 0.f)));
                    float ta = fmaf(sc[0], hh[0], fmaf(sc[2], hh[2], sc[4]*hh[4]));
                    float tb = fmaf(sc[1], hh[1], fmaf(sc[3], hh[3], sc[5]*hh[5]));
                    float md = fdot2u(tE.z, hhp0, fdot2u(tE.w, hhp1,
                               fdot2u(tF.x, hhp2, vv_[lr])));
                    float nd = fdot2u(tF.y, hvh0, fdot2u(tF.z, hvh1,
                               fdot2u(tF.w, hvh2, 0.f)));
                    acc[lr] = (ta + tb) + (md + nd);
                }
                float q0_ = acc[0]*acc[0], q1_ = acc[1]*acc[1], q2_ = acc[2]*acc[2];
                float ssl = (q0_ + q1_) + q2_;
                float pq  = fmaf(e2_[0], q0_, fmaf(e2_[1], q1_, e2_[2] * q2_));
                float s1  = ssl + DPPF(ssl, QP_XOR1);
                float ssq = s1 + DPPF(s1, QP_XOR2);
                float p1  = pq + DPPF(pq, QP_XOR1);
                float px  = DPPF(p1, QP_XOR2);
                const float inv = FAST_RSQ(ssq + 1e-12f);
                const int sel = (cbr >> qq) & 1;
                const float qsel = (mya == sel) ? p1 : px;
                amp2 *= qsel * FAST_RCP(p1 + px);
                float an0 = acc[0] * inv, an1 = acc[1] * inv, an2 = acc[2] * inv;
                float sw0 = DPPF(an0, QP_XOR2);
                float sw1 = DPPF(an1, QP_XOR2);
                float sw2 = DPPF(an2, QP_XOR2);
                an0 = sel ? sw0 : an0;
                an1 = sel ? sw1 : an1;
                an2 = sel ? sw2 : an2;
                hh[0] = DPPF(an0, QP_BC0); hh[3] = DPPF(an0, QP_BC1);
                hh[1] = DPPF(an1, QP_BC0); hh[4] = DPPF(an1, QP_BC1);
                hh[2] = DPPF(an2, QP_BC0); hh[5] = DPPF(an2, QP_BC1);
                hhp0 = pack2(hh[0], hh[1]);
                hhp1 = pack2(hh[2], hh[3]);
                hhp2 = pack2(hh[4], hh[5]);
                uint4 wv = Wl[slot];
                phi = fdot2u(wv.x, hhp0, fdot2u(wv.y, hhp1,
                      fdot2u(wv.z, hhp2, __uint_as_float(wv.w) + phi)));
                if (sub == 0) {
                    *reinterpret_cast<uint4*>(vsm + j * 256 + s * 4) =
                        make_uint4(h2u(hhp0), h2u(hhp1), h2u(hhp2), 0u);
                }
            }
        }
    }

    if (sub == 0 && valid) {
        const float amp = sqrtf(amp2);
        if (writeImag) {
            out[2 * b + 0] = amp * cosf(phi);
            out[2 * b + 1] = amp * sinf(phi);
        } else {
            out[b] = amp * cosf(phi);
        }
    }
}

extern "C" void kernel_launch(void* const* d_in, const int* in_sizes, int n_in,
                              void* d_out, int out_size, void* d_ws, size_t ws_size,
                              hipStream_t stream) {
    const float* Mh = (const float*)d_in[0];
    const float* Mv = (const float*)d_in[1];
    const float* Vp = (const float*)d_in[2];
    const float* Tp = (const float*)d_in[3];
    const float* Wp = (const float*)d_in[4];
    const float* Cp = (const float*)d_in[5];
    const float* Ep = (const float*)d_in[6];
    const int*   X  = (const int*)d_in[7];
    float* out = (float*)d_out;

    const int Bn = in_sizes[7] / NQ;                 // 32768
    const int writeImag = (out_size >= 2 * Bn) ? 1 : 0;

    const size_t need = (size_t)4 * CHUNK_U * sizeof(unsigned);  // 82944 B
    if (ws_size >= need) {
        repack_k<<<4, BT, 0, stream>>>(Mh, Mv, Vp, Tp, Wp, Cp, Ep,
                                       (unsigned*)d_ws);
        const int grid = (Bn + 127) / 128;           // 256 blocks, 2 samples/thread
        mps_rnn21<<<grid, BT, 0, stream>>>((const unsigned*)d_ws, X, out,
                                           Bn, writeImag);
    } else {
        const int grid = (Bn + 63) / 64;
        mps_rnn16fb<<<grid, BT, 0, stream>>>(Mh, Mv, Vp, Tp, Wp, Cp, Ep, X,
                                             out, Bn, writeImag);
    }
}